// Round 8
// baseline (468.064 us; speedup 1.0000x reference)
//
#include <hip/hip_runtime.h>
#include <hip/hip_bf16.h>

#define D 64
#define FP_SCALE 262144.0f          // 2^18 (order-free int accumulation)
#define FP_INV   (1.0f / 262144.0f)
#define CHUNK 512                   // edges per aggregate block
#define SLOTS 128                   // LDS dst slots (32 KB) — span avg ~64

__device__ __forceinline__ unsigned short f2bf(float f) {   // rtne f32->bf16
    unsigned int u = __float_as_uint(f);
    u += 0x7fffu + ((u >> 16) & 1u);
    return (unsigned short)(u >> 16);
}

// ---------- CSR build (deterministic, dst-sorted) ----------
__global__ void hist_kernel(const int* __restrict__ dst, int* __restrict__ counts, int E) {
    int e = blockIdx.x * blockDim.x + threadIdx.x;
    if (e < E) atomicAdd(&counts[dst[e]], 1);
}

// per-block(256) sums of counts
__global__ void part_kernel(const int* __restrict__ counts, int* __restrict__ partial, int N) {
    __shared__ int ws4[4];
    int t = threadIdx.x, lane = t & 63, w = t >> 6;
    int n = blockIdx.x * 256 + t;
    int c = (n < N) ? counts[n] : 0;
    #pragma unroll
    for (int off = 32; off > 0; off >>= 1) c += __shfl_down(c, off);
    if (lane == 0) ws4[w] = c;
    __syncthreads();
    if (t == 0) partial[blockIdx.x] = ws4[0] + ws4[1] + ws4[2] + ws4[3];
}

// single-block exclusive scan of partials (any nb, 512-wide passes with carry)
__global__ void scan_kernel(int* __restrict__ partial, int nb) {
    __shared__ int wsum[8];
    int t = threadIdx.x, lane = t & 63, w = t >> 6;
    int carry = 0;
    for (int base = 0; base < nb; base += 512) {
        int i = base + t;
        int v = (i < nb) ? partial[i] : 0;
        int incl = v;
        #pragma unroll
        for (int off = 1; off < 64; off <<= 1) {
            int x = __shfl_up(incl, off);
            if (lane >= off) incl += x;
        }
        if (lane == 63) wsum[w] = incl;
        __syncthreads();
        int wpre = 0;
        for (int j = 0; j < w; ++j) wpre += wsum[j];
        int tot = 0;
        for (int j = 0; j < 8; ++j) tot += wsum[j];
        if (i < nb) partial[i] = carry + wpre + incl - v;
        carry += tot;
        __syncthreads();
    }
}

// seg[n] = (global exclusive prefix, count); cursor seeded for fill.
__global__ void seg_kernel(const int* __restrict__ counts, const int* __restrict__ partial,
                           int2* __restrict__ seg, int* __restrict__ cursor, int N) {
    __shared__ int ws4[4];
    int t = threadIdx.x, lane = t & 63, w = t >> 6;
    int n = blockIdx.x * 256 + t;
    int c = (n < N) ? counts[n] : 0;
    int incl = c;
    #pragma unroll
    for (int off = 1; off < 64; off <<= 1) {
        int x = __shfl_up(incl, off);
        if (lane >= off) incl += x;
    }
    if (lane == 63) ws4[w] = incl;
    __syncthreads();
    int wpre = 0;
    for (int j = 0; j < w; ++j) wpre += ws4[j];
    int st = partial[blockIdx.x] + wpre + incl - c;
    if (n < N) {
        seg[n] = make_int2(st, c);
        cursor[n] = st;
    }
}

// perm is globally dst-sorted (scan-based starts); within-segment order is
// atomic-arrival nondeterministic, but int accumulation is order-free.
__global__ void fill_kernel(const int* __restrict__ src, const int* __restrict__ dst,
                            const float* __restrict__ ew, int* __restrict__ cursor,
                            float2* __restrict__ perm, int* __restrict__ permDst, int E) {
    int e = blockIdx.x * blockDim.x + threadIdx.x;
    if (e < E) {
        int d = dst[e];
        int p = atomicAdd(&cursor[d], 1);
        perm[p] = make_float2(__int_as_float(src[e]), ew[e] * FP_SCALE);
        permDst[p] = d;
    }
}

// f32 -> bf16 convert (for iteration 0 input)
__global__ void cvt_kernel(const float* __restrict__ in, unsigned short* __restrict__ out, int n4) {
    int i = blockIdx.x * blockDim.x + threadIdx.x;
    if (i >= n4) return;
    float4 v = reinterpret_cast<const float4*>(in)[i];
    ushort4 o;
    o.x = f2bf(v.x); o.y = f2bf(v.y); o.z = f2bf(v.z); o.w = f2bf(v.w);
    reinterpret_cast<ushort4*>(out)[i] = o;
}

// ---------- edge-parallel aggregate ----------
// Block owns CHUNK consecutive (dst-sorted) edges -> a contiguous dst range.
// 16-lane groups stream edges (bf16 row segment per lane: 4 feats = 8B),
// int fixed-point accumulate into LDS slot table via ds atomics (order-free).
// Flush: interior dst (segment fully inside chunk) -> plain store; boundary
// dst -> global int atomicAdd into zeroed agg. All loads independent -> MLP
// limited only by occupancy, not node degree.
__global__ void agg_kernel(const unsigned short* __restrict__ xb,
                           const float2* __restrict__ perm,
                           const int* __restrict__ permDst,
                           const int2* __restrict__ seg,
                           int* __restrict__ agg, int E) {
    __shared__ int acc[SLOTS * D];
    int t = threadIdx.x;
    int base = blockIdx.x * CHUNK;
    int end = min(base + CHUNK, E);
    int slotBase = permDst[base];
    int span = permDst[end - 1] - slotBase + 1;
    int zspan = min(span, SLOTS);
    for (int i = t; i < zspan * D; i += 256) acc[i] = 0;
    __syncthreads();

    int g = t >> 4;              // edge sub-stream 0..15
    int c = (t & 15) << 2;       // feature base
    for (int e = base + g; e < end; e += 16) {
        int dn = permDst[e];
        float2 m = perm[e];
        int s = __float_as_int(m.x);
        float w = m.y;           // pre-scaled by 2^18
        uint2 u = *reinterpret_cast<const uint2*>(&xb[(size_t)s * D + c]);
        int v0 = (int)(w * __uint_as_float(u.x << 16));
        int v1 = (int)(w * __uint_as_float(u.x & 0xffff0000u));
        int v2 = (int)(w * __uint_as_float(u.y << 16));
        int v3 = (int)(w * __uint_as_float(u.y & 0xffff0000u));
        int slot = dn - slotBase;
        if (slot < SLOTS) {
            atomicAdd(&acc[slot * D + c + 0], v0);
            atomicAdd(&acc[slot * D + c + 1], v1);
            atomicAdd(&acc[slot * D + c + 2], v2);
            atomicAdd(&acc[slot * D + c + 3], v3);
        } else {                 // overflow (statistically never at deg~8)
            size_t o = (size_t)dn * D + c;
            atomicAdd(&agg[o + 0], v0);
            atomicAdd(&agg[o + 1], v1);
            atomicAdd(&agg[o + 2], v2);
            atomicAdd(&agg[o + 3], v3);
        }
    }
    __syncthreads();

    int wave = t >> 6, lane = t & 63;
    for (int s = wave; s < zspan; s += 4) {
        int node = slotBase + s;
        int2 sg = seg[node];
        int v = acc[s * D + lane];
        bool interior = (sg.x >= base) && (sg.x + sg.y <= end);
        size_t o = (size_t)node * D + lane;
        if (interior) agg[o] = v;                 // sole writer
        else if (v) atomicAdd(&agg[o], v);        // partial into zeroed agg
    }
}

// ---------- dense linear + relu ----------
// Wave per node: coalesced agg-row load -> LDS row broadcast (b128 reads),
// 64 fmas against W row held in VGPRs (launch_bounds 4 waves/EU -> 128 VGPR
// budget keeps wreg resident; round-7 failed this at the default 64).
template<bool OUT_BF>
__launch_bounds__(256, 4)
__global__ void linear_kernel(const int* __restrict__ agg,
                              const float* __restrict__ W,
                              const float* __restrict__ bias,
                              void* __restrict__ xout, int N) {
    __shared__ float rowSh[4][D];
    int t = threadIdx.x, wave = t >> 6, lane = t & 63;
    float4 wreg[16];
    #pragma unroll
    for (int q = 0; q < 16; ++q)
        wreg[q] = *reinterpret_cast<const float4*>(&W[(size_t)lane * D + 4 * q]);
    float bl = bias[lane];
    int nwaves = gridDim.x * 4;
    for (int n = blockIdx.x * 4 + wave; n < N; n += nwaves) {
        int v = agg[(size_t)n * D + lane];        // coalesced 256B row
        rowSh[wave][lane] = (float)v * FP_INV;    // same-wave write->read, in order
        float o0 = 0.f, o1 = 0.f, o2 = 0.f, o3 = 0.f;
        #pragma unroll
        for (int q = 0; q < 16; ++q) {
            float4 a = *reinterpret_cast<const float4*>(&rowSh[wave][4 * q]);
            o0 = fmaf(a.x, wreg[q].x, o0);
            o1 = fmaf(a.y, wreg[q].y, o1);
            o2 = fmaf(a.z, wreg[q].z, o2);
            o3 = fmaf(a.w, wreg[q].w, o3);
        }
        float o = fmaxf(bl + ((o0 + o1) + (o2 + o3)), 0.0f);
        if (OUT_BF) ((unsigned short*)xout)[(size_t)n * D + lane] = f2bf(o);
        else        ((float*)xout)[(size_t)n * D + lane] = o;
    }
}

// ---------- fallback (int-atomic path, deterministic, f32) if ws too small ----------
__global__ void rpi_scatter_kernel(const float* __restrict__ x,
                                   const int* __restrict__ src,
                                   const int* __restrict__ dst,
                                   const float* __restrict__ ew,
                                   int* __restrict__ agg, int E) {
    int tid = blockIdx.x * blockDim.x + threadIdx.x;
    int e = tid >> 4;
    if (e >= E) return;
    int c = (tid & 15) << 2;
    int s = src[e], d = dst[e];
    float w = ew[e] * FP_SCALE;
    float4 v = *reinterpret_cast<const float4*>(&x[(size_t)s * D + c]);
    int* o = &agg[(size_t)d * D + c];
    atomicAdd(o + 0, (int)(w * v.x));
    atomicAdd(o + 1, (int)(w * v.y));
    atomicAdd(o + 2, (int)(w * v.z));
    atomicAdd(o + 3, (int)(w * v.w));
}

__global__ void rpi_linear_relu_kernel(const int* __restrict__ agg,
                                       const float* __restrict__ W,
                                       const float* __restrict__ b,
                                       float* __restrict__ out, int N) {
    __shared__ float Ws[D][D + 1];
    __shared__ float bs[D];
    int t = threadIdx.x;
    for (int i = t; i < D * D; i += 256) Ws[i >> 6][i & 63] = W[i];
    if (t < D) bs[t] = b[t];
    __syncthreads();
    int wave = t >> 6, lane = t & 63;
    int nwaves = gridDim.x * 4;
    for (int n = blockIdx.x * 4 + wave; n < N; n += nwaves) {
        const int* arow = &agg[(size_t)n * D];
        float acc = bs[lane];
        #pragma unroll
        for (int d = 0; d < D; ++d) acc = fmaf((float)arow[d] * FP_INV, Ws[lane][d], acc);
        out[(size_t)n * D + lane] = fmaxf(acc, 0.0f);
    }
}

extern "C" void kernel_launch(void* const* d_in, const int* in_sizes, int n_in,
                              void* d_out, int out_size, void* d_ws, size_t ws_size,
                              hipStream_t stream) {
    const float* x0 = (const float*)d_in[0];   // [N, 64]
    const int*   ei = (const int*)d_in[1];     // [2, E]
    const float* ew = (const float*)d_in[2];   // [E]
    const float* W  = (const float*)d_in[3];   // [64, 64]
    const float* b  = (const float*)d_in[4];   // [64]
    float* out = (float*)d_out;                // [N, 64]

    int N = in_sizes[0] / D;
    int E = in_sizes[2];
    const int* src = ei;
    const int* dst = ei + E;

    int nb = (N + 255) / 256;
    size_t xeb = (size_t)N * D * sizeof(unsigned short);   // 12.8 MB
    size_t off = 0;
    size_t o_xb1  = off; off += xeb;
    size_t o_xb2  = off; off += xeb;
    size_t o_perm = off; off += (size_t)E * sizeof(float2);
    size_t o_pdst = off; off += (size_t)E * sizeof(int);
    size_t o_seg  = off; off += (size_t)N * sizeof(int2);
    size_t o_cnt  = off; off += (size_t)N * sizeof(int);
    size_t o_part = off; off += ((size_t)nb + 16) * sizeof(int);
    size_t need = off;

    if (ws_size >= need) {
        unsigned short* xb1 = (unsigned short*)((char*)d_ws + o_xb1);
        unsigned short* xb2 = (unsigned short*)((char*)d_ws + o_xb2);
        float2* perm    = (float2*)((char*)d_ws + o_perm);
        int*    permDst = (int*)((char*)d_ws + o_pdst);
        int2*   seg     = (int2*)((char*)d_ws + o_seg);
        int*    cnt_cur = (int*)((char*)d_ws + o_cnt);   // counts, then cursor
        int*    partial = (int*)((char*)d_ws + o_part);
        int*    agg     = (int*)d_out;                    // int agg aliases d_out

        int eb = (E + 255) / 256;
        int n4 = N * D / 4;
        int ab = (E + CHUNK - 1) / CHUNK;

        hipMemsetAsync(cnt_cur, 0, (size_t)N * sizeof(int), stream);
        hist_kernel<<<eb, 256, 0, stream>>>(dst, cnt_cur, E);
        part_kernel<<<nb, 256, 0, stream>>>(cnt_cur, partial, N);
        scan_kernel<<<1, 512, 0, stream>>>(partial, nb);
        seg_kernel <<<nb, 256, 0, stream>>>(cnt_cur, partial, seg, cnt_cur, N);
        fill_kernel<<<eb, 256, 0, stream>>>(src, dst, ew, cnt_cur, perm, permDst, E);
        cvt_kernel <<<(n4 + 255) / 256, 256, 0, stream>>>(x0, xb1, n4);

        // iter 0
        hipMemsetAsync(agg, 0, (size_t)N * D * sizeof(int), stream);
        agg_kernel<<<ab, 256, 0, stream>>>(xb1, perm, permDst, seg, agg, E);
        linear_kernel<true><<<2048, 256, 0, stream>>>(agg, W, b, xb2, N);
        // iter 1
        hipMemsetAsync(agg, 0, (size_t)N * D * sizeof(int), stream);
        agg_kernel<<<ab, 256, 0, stream>>>(xb2, perm, permDst, seg, agg, E);
        linear_kernel<true><<<2048, 256, 0, stream>>>(agg, W, b, xb1, N);
        // iter 2 (linear reads agg=d_out, writes f32 d_out: each row owned by
        // exactly one wave, loads precede stores -> safe aliasing)
        hipMemsetAsync(agg, 0, (size_t)N * D * sizeof(int), stream);
        agg_kernel<<<ab, 256, 0, stream>>>(xb1, perm, permDst, seg, agg, E);
        linear_kernel<false><<<2048, 256, 0, stream>>>(agg, W, b, out, N);
    } else {
        int* agg = (int*)d_ws;
        const float* xcur = x0;
        int sb = (E * 16 + 255) / 256;
        for (int it = 0; it < 3; ++it) {
            hipMemsetAsync(agg, 0, (size_t)N * D * sizeof(int), stream);
            rpi_scatter_kernel<<<sb, 256, 0, stream>>>(xcur, src, dst, ew, agg, E);
            rpi_linear_relu_kernel<<<2048, 256, 0, stream>>>(agg, W, b, out, N);
            xcur = out;
        }
    }
}